// Round 1
// baseline (285.967 us; speedup 1.0000x reference)
//
#include <hip/hip_runtime.h>
#include <stdint.h>

#define TT 25
#define SS 512
#define BB 4096
#define INVLN2 1.4426950408889634f
#define LN2F   0.6931471805599453f

__device__ __forceinline__ float ex2(float x){ return __builtin_amdgcn_exp2f(x); }
__device__ __forceinline__ float lg2(float x){ return __builtin_amdgcn_logf(x); }
// broadcast lane l's value to all lanes via SGPR
__device__ __forceinline__ float rl(float v, int l){
  return __int_as_float(__builtin_amdgcn_readlane(__float_as_int(v), l));
}

// mask may arrive as bool(u8), int32, or float32 — detect from first element
__device__ __forceinline__ int mask_at(const void* m, int mode, long idx){
  if (mode == 1) return ((const int*)m)[idx] != 0;
  if (mode == 2) return ((const float*)m)[idx] != 0.0f;
  return ((const unsigned char*)m)[idx] != 0;
}

__global__ __launch_bounds__(256, 4)
void crf_main(const float* __restrict__ em, const float* __restrict__ startp,
              const float* __restrict__ endp, const float* __restrict__ transp,
              const int* __restrict__ labels, const void* __restrict__ maskp,
              float* __restrict__ wsr, float* __restrict__ wsl)
{
  const int lane = threadIdx.x & 63;
  const int b = __builtin_amdgcn_readfirstlane(blockIdx.x * 4 + (threadIdx.x >> 6));
  const int jj = lane & 31;          // lanes 32..63 mirror 0..31 (idle duplicates)
  const bool jv = jj < TT;
  const int jc = jv ? jj : (TT - 1); // clamped column for safe addresses

  // --- mask dtype detection (mask[.,0] is always true since len>=256) ---
  const uint32_t w0 = ((const uint32_t*)maskp)[0];
  const int mode = (w0 == 1u) ? 1 : ((w0 == 0x3F800000u) ? 2 : 0);

  // --- sequence length via 2-round ballot probe (mask is a prefix mask) ---
  const long mb = (long)b * SS;
  int p1 = mask_at(maskp, mode, mb + lane * 8);           // probes 0,8,...,504
  unsigned long long b1 = __ballot(p1);
  int q = __popcll(b1);                                   // ceil(len/8)
  int base2 = 8 * (q - 1);
  int p2 = mask_at(maskp, mode, mb + base2 + (lane & 7));
  unsigned long long b2 = __ballot((lane < 8) && p2);
  const int len = base2 + __popcll(b2);                   // wave-uniform

  const float* emrow = em + (size_t)b * (SS * TT);

  // --- etrans column j in registers (exp of transitions), zeroed for j>=25 ---
  float Ecol[TT];
#pragma unroll
  for (int i = 0; i < TT; ++i) {
    float tv = transp[i * TT + jc];
    Ecol[i] = jv ? ex2(tv * INVLN2) : 0.0f;
  }

  // --- init: alpha0 = start + em[:,0] in linear domain ---
  float em0 = emrow[jc];
  float pj = jv ? ex2((startp[jc] + em0) * INVLN2) : 0.0f;

  float sp[TT];
#pragma unroll
  for (int i = 0; i < TT; ++i) sp[i] = rl(pj, i);

  const int l0 = labels[mb];
  float num = startp[l0] + rl(em0, l0);
  float C2 = 0.0f, C2c = 0.0f;   // log2 scale accumulator (Kahan)
  int last = l0;

  int   lab_cur = labels[mb + 1];
  float em_cur  = emrow[TT + jc];
  float t_cur   = transp[l0 * TT + lab_cur];

  for (int s = 1; s < len; ++s) {
    // prefetch next step's emission element + label (clamped at the end)
    int sn = (s + 1 < len) ? (s + 1) : (len - 1);
    float em_next = emrow[(size_t)sn * TT + jc];
    int   lab_next = labels[mb + sn];

    // dot: p'_j = sum_i p_i * etrans[i][j]   (p_i broadcast from SGPRs)
    float acc = sp[0] * Ecol[0];
#pragma unroll
    for (int i = 1; i < TT; ++i) acc = fmaf(sp[i], Ecol[i], acc);
    float pnew = acc * ex2(em_cur * INVLN2);

    // numerator: trans[l_{s-1}, l_s] (prefetched) + em[b,s,l_s]
    num += t_cur;
    num += rl(em_cur, lab_cur);

    // periodic rescale to keep p in fp32 range (growth ~e^3.7/step)
    if ((s & 3) == 0) {
      float m = pnew;
      m = fmaxf(m, __shfl_xor(m, 1, 32));
      m = fmaxf(m, __shfl_xor(m, 2, 32));
      m = fmaxf(m, __shfl_xor(m, 4, 32));
      m = fmaxf(m, __shfl_xor(m, 8, 32));
      m = fmaxf(m, __shfl_xor(m, 16, 32));
      pnew = pnew * __builtin_amdgcn_rcpf(m);
      float y = lg2(m) - C2c;
      float t = C2 + y;
      C2c = (t - C2) - y;
      C2 = t;
    }

    pj = pnew;
#pragma unroll
    for (int i = 0; i < TT; ++i) sp[i] = rl(pj, i);

    t_cur  = transp[lab_cur * TT + lab_next];  // prefetch next trans score
    last   = lab_cur;
    lab_cur = lab_next;
    em_cur  = em_next;
  }

  num += endp[last];

  // denominator = ln2 * (log2(sum_j p_j * 2^(end_j/ln2)) + C2)
  float term = jv ? pj * ex2(endp[jc] * INVLN2) : 0.0f;
  term += __shfl_xor(term, 1, 32);
  term += __shfl_xor(term, 2, 32);
  term += __shfl_xor(term, 4, 32);
  term += __shfl_xor(term, 8, 32);
  term += __shfl_xor(term, 16, 32);
  float den = LN2F * (lg2(term) + C2);

  if (lane == 0) {
    wsr[b] = num - den;
    wsl[b] = (float)len;
  }
}

__global__ void crf_reduce(const float* __restrict__ wsr,
                           const float* __restrict__ wsl,
                           float* __restrict__ out)
{
  __shared__ float sr[256], sl[256];
  int t = threadIdx.x;
  float a = 0.0f, c = 0.0f;
  for (int i = t; i < BB; i += 256) { a += wsr[i]; c += wsl[i]; }
  sr[t] = a; sl[t] = c;
  __syncthreads();
  for (int k = 128; k > 0; k >>= 1) {
    if (t < k) { sr[t] += sr[t + k]; sl[t] += sl[t + k]; }
    __syncthreads();
  }
  if (t == 0) out[0] = sr[0] / sl[0];
}

extern "C" void kernel_launch(void* const* d_in, const int* in_sizes, int n_in,
                              void* d_out, int out_size, void* d_ws, size_t ws_size,
                              hipStream_t stream)
{
  const float* em = (const float*)d_in[0];
  const float* st = (const float*)d_in[1];
  const float* en = (const float*)d_in[2];
  const float* tr = (const float*)d_in[3];
  const int*   lb = (const int*)d_in[4];
  const void*  mk = d_in[5];
  float* wsr = (float*)d_ws;
  float* wsl = wsr + BB;
  crf_main<<<BB / 4, 256, 0, stream>>>(em, st, en, tr, lb, mk, wsr, wsl);
  crf_reduce<<<1, 256, 0, stream>>>(wsr, wsl, (float*)d_out);
}

// Round 2
// 284.978 us; speedup vs baseline: 1.0035x; 1.0035x over previous
//
#include <hip/hip_runtime.h>
#include <stdint.h>

#define TT 25
#define SS 512
#define BB 4096
#define INVLN2 1.4426950408889634f
#define LN2F   0.6931471805599453f

__device__ __forceinline__ float ex2(float x){ return __builtin_amdgcn_exp2f(x); }
__device__ __forceinline__ float lg2(float x){ return __builtin_amdgcn_logf(x); }
__device__ __forceinline__ float bperm(int idx, float v){
  return __int_as_float(__builtin_amdgcn_ds_bpermute(idx, __float_as_int(v)));
}
__device__ __forceinline__ float rlanef(float v, int l){
  return __int_as_float(__builtin_amdgcn_readlane(__float_as_int(v), l));
}

// mask may arrive as bool(u8), int32, or float32 — detect from first element
__device__ __forceinline__ int mask_at(const void* m, int mode, int idx){
  if (mode == 1) return ((const int*)m)[idx] != 0;
  if (mode == 2) return ((const float*)m)[idx] != 0.0f;
  return ((const unsigned char*)m)[idx] != 0;
}

__global__ __launch_bounds__(256, 2)
void crf_main(const float* __restrict__ em, const float* __restrict__ startp,
              const float* __restrict__ endp, const float* __restrict__ transp,
              const int* __restrict__ labels, const void* __restrict__ maskp,
              float* __restrict__ wsr, float* __restrict__ wsl)
{
  const int lane = threadIdx.x & 63;
  // force wave-uniformity so label/trans ring loads become scalar loads
  const int b = __builtin_amdgcn_readfirstlane(blockIdx.x * 4 + (threadIdx.x >> 6));
  const int jj = lane & 31;
  const bool jv = jj < TT;
  const int jc = jv ? jj : (TT - 1);
  const bool up = lane >= 32;

  // --- mask dtype detection (mask[.,0] is always true since len>=256) ---
  const uint32_t w0 = ((const uint32_t*)maskp)[0];
  const int mode = (w0 == 1u) ? 1 : ((w0 == 0x3F800000u) ? 2 : 0);

  // --- sequence length via 2-round ballot probe (mask is a prefix mask) ---
  const int mb = b * SS;
  int p1 = mask_at(maskp, mode, mb + lane * 8);
  unsigned long long b1 = __ballot(p1);
  int q = __popcll(b1);
  int base2 = 8 * (q - 1);
  int p2 = mask_at(maskp, mode, mb + base2 + (lane & 7));
  unsigned long long b2 = __ballot((lane < 8) && p2);
  const int len = base2 + __popcll(b2);
  const int nsteps = len - 1;

  const float* emrow = em + (size_t)b * (SS * TT);

  // --- etrans split across halves: lower k -> i=k (0..12), upper k -> i=13+k (k=12 dead) ---
  float Ecol[13];
  int   bidx[13];
#pragma unroll
  for (int k = 0; k < 13; ++k) {
    int i  = up ? (13 + k) : k;
    bool iv = (i < TT);
    int ic = iv ? i : (TT - 1);
    float tvx = transp[ic * TT + jc];
    Ecol[k] = (iv && jv) ? ex2(tvx * INVLN2) : 0.0f;
    bidx[k] = 4 * ic;   // ds_bpermute byte index = 4*src_lane (pulls from lanes 0..24)
  }

  // --- init: alpha0 = exp2((start + em0)/ln2), valid in lanes 0..24 (both halves) ---
  float em0 = emrow[jc];
  float p = jv ? ex2((startp[jc] + em0) * INVLN2) : 0.0f;

  const int l0 = labels[mb];
  float num2 = (startp[l0] + rlanef(em0, l0)) * INVLN2;  // numerator in log2 units
  int C2i = 0;                                           // exact power-of-2 scale count

  // --- prefetch rings, depth 8 ---
  float emv[8];
  int   labv[8];
  float tvv[8];
#pragma unroll
  for (int u = 0; u < 8; ++u) {
    emv[u]  = emrow[(1 + u) * TT + jc];
    labv[u] = labels[mb + 1 + u];
  }
  int fl = l0;  // label of most recently filled step minus one (fill-stream carry)
#pragma unroll
  for (int u = 0; u < 8; ++u) { tvv[u] = transp[fl * TT + labv[u]]; fl = labv[u]; }

  int t = 1;

#define STEP(u, FILL)                                                          \
  {                                                                            \
    float em2   = emv[u] * INVLN2;                                             \
    int   lab_u = labv[u];                                                     \
    float tv_u  = tvv[u];                                                      \
    if (FILL) {                                                                \
      int sn = t + (u) + 8; if (sn > nsteps) sn = nsteps;                      \
      emv[u] = emrow[sn * TT + jc];                                            \
      int nl = labels[mb + sn];                                                \
      tvv[u] = transp[fl * TT + nl];                                           \
      labv[u] = nl;                                                            \
      fl = nl;                                                                 \
    }                                                                          \
    float a0 = bperm(bidx[0], p) * Ecol[0];                                    \
    float a1 = bperm(bidx[1], p) * Ecol[1];                                    \
    a0 = fmaf(bperm(bidx[2],  p), Ecol[2],  a0);                               \
    a1 = fmaf(bperm(bidx[3],  p), Ecol[3],  a1);                               \
    a0 = fmaf(bperm(bidx[4],  p), Ecol[4],  a0);                               \
    a1 = fmaf(bperm(bidx[5],  p), Ecol[5],  a1);                               \
    a0 = fmaf(bperm(bidx[6],  p), Ecol[6],  a0);                               \
    a1 = fmaf(bperm(bidx[7],  p), Ecol[7],  a1);                               \
    a0 = fmaf(bperm(bidx[8],  p), Ecol[8],  a0);                               \
    a1 = fmaf(bperm(bidx[9],  p), Ecol[9],  a1);                               \
    a0 = fmaf(bperm(bidx[10], p), Ecol[10], a0);                               \
    a1 = fmaf(bperm(bidx[11], p), Ecol[11], a1);                               \
    a0 = fmaf(bperm(bidx[12], p), Ecol[12], a0);                               \
    float al = a0 + a1;                                                        \
    float ps = al + __shfl_xor(al, 32);   /* combine lower(i=0..12)+upper(13..24) */ \
    p = ps * ex2(em2);                                                         \
    num2 = fmaf(tv_u, INVLN2, num2);                                           \
    num2 += rlanef(em2, lab_u);                                                \
  }

  for (; t + 7 <= nsteps; t += 8) {
    STEP(0, 1) STEP(1, 1) STEP(2, 1) STEP(3, 1)
    STEP(4, 1) STEP(5, 1) STEP(6, 1) STEP(7, 1)
    // exact power-of-2 rescale from lane-0 exponent (p_0 within 2^15 of max col)
    int pb = __builtin_amdgcn_readlane(__float_as_int(p), 0);
    int ef = (pb >> 23) & 0xFF;
    C2i += ef - 127;
    p *= __int_as_float((254 - ef) << 23);   // exact 2^(127-ef)
  }
  int rem = nsteps - t + 1;   // 0..7 remaining steps, ring slots 0..rem-1 hold them
  if (rem > 0) STEP(0, 0)
  if (rem > 1) STEP(1, 0)
  if (rem > 2) STEP(2, 0)
  if (rem > 3) STEP(3, 0)
  if (rem > 4) STEP(4, 0)
  if (rem > 5) STEP(5, 0)
  if (rem > 6) STEP(6, 0)

#undef STEP

  const int last = labels[mb + nsteps];
  num2 = fmaf(endp[last], INVLN2, num2);

  // denominator: log2(sum_j p_j * 2^(end_j/ln2)) + C2i
  float term = jv ? p * ex2(endp[jc] * INVLN2) : 0.0f;
  term += __shfl_xor(term, 1);
  term += __shfl_xor(term, 2);
  term += __shfl_xor(term, 4);
  term += __shfl_xor(term, 8);
  term += __shfl_xor(term, 16);
  float den2 = lg2(term) + (float)C2i;

  if (lane == 0) {
    wsr[b] = LN2F * (num2 - den2);
    wsl[b] = (float)len;
  }
}

__global__ void crf_reduce(const float* __restrict__ wsr,
                           const float* __restrict__ wsl,
                           float* __restrict__ out)
{
  __shared__ float sr[256], sl[256];
  int t = threadIdx.x;
  float a = 0.0f, c = 0.0f;
  for (int i = t; i < BB; i += 256) { a += wsr[i]; c += wsl[i]; }
  sr[t] = a; sl[t] = c;
  __syncthreads();
  for (int k = 128; k > 0; k >>= 1) {
    if (t < k) { sr[t] += sr[t + k]; sl[t] += sl[t + k]; }
    __syncthreads();
  }
  if (t == 0) out[0] = sr[0] / sl[0];
}

extern "C" void kernel_launch(void* const* d_in, const int* in_sizes, int n_in,
                              void* d_out, int out_size, void* d_ws, size_t ws_size,
                              hipStream_t stream)
{
  const float* em = (const float*)d_in[0];
  const float* st = (const float*)d_in[1];
  const float* en = (const float*)d_in[2];
  const float* tr = (const float*)d_in[3];
  const int*   lb = (const int*)d_in[4];
  const void*  mk = d_in[5];
  float* wsr = (float*)d_ws;
  float* wsl = wsr + BB;
  crf_main<<<BB / 4, 256, 0, stream>>>(em, st, en, tr, lb, mk, wsr, wsl);
  crf_reduce<<<1, 256, 0, stream>>>(wsr, wsl, (float*)d_out);
}

// Round 3
// 134.869 us; speedup vs baseline: 2.1203x; 2.1130x over previous
//
#include <hip/hip_runtime.h>
#include <stdint.h>

#define TT 25
#define SS 512
#define BB 4096
#define RST 48      // LDS row stride in floats (bank-shifts rows, gives dump slots)
#define IL2 1.4426950408889634f
#define LN2F 0.6931471805599453f

__device__ __forceinline__ float ex2(float x){ return __builtin_amdgcn_exp2f(x); }
__device__ __forceinline__ float lg2(float x){ return __builtin_amdgcn_logf(x); }

// mask may arrive as bool(u8), int32, or float32 — detect from first element
__device__ __forceinline__ int mask_at(const void* m, int mode, int idx){
  if (mode == 1) return ((const int*)m)[idx] != 0;
  if (mode == 2) return ((const float*)m)[idx] != 0.0f;
  return ((const unsigned char*)m)[idx] != 0;
}

__global__ __launch_bounds__(256, 1)
void crf_main(const float* __restrict__ em, const float* __restrict__ startp,
              const float* __restrict__ endp, const float* __restrict__ transp,
              const int* __restrict__ labels, const void* __restrict__ maskp,
              float* __restrict__ wsr, float* __restrict__ wsl)
{
  __shared__ float smem[16 * RST];   // 4 waves x 4 rows x 48 floats = 3 KB
  const int tid  = threadIdx.x;
  const int w    = tid >> 6;
  const int lane = tid & 63;
  const int g    = lane >> 4;        // row-group 0..3 within wave
  const int lidx = lane & 15;        // 0..12 = active columns, 13..15 idle
  const int rowid = blockIdx.x * 16 + w * 4 + g;
  const int rbS   = rowid * SS;

  const int col1  = (lidx < 13) ? lidx : 12;          // columns 0..12
  const int col2  = (lidx + 13 < TT) ? (lidx + 13) : (TT - 1);  // 13..24 (lane12 dup 24)
  const int wslot = (lidx < 13) ? lidx : 28;          // idle lanes dump to padding
  const int rowbase = (w * 4 + g) * RST;

  // --- mask dtype detection ---
  const uint32_t w0 = ((const uint32_t*)maskp)[0];
  const int mode = (w0 == 1u) ? 1 : ((w0 == 0x3F800000u) ? 2 : 0);

  // --- per-row lengths: 4 sequential full-wave 2-round ballot probes ---
  int lens[4];
  const int blockrow0 = blockIdx.x * 16 + w * 4;
#pragma unroll
  for (int r = 0; r < 4; ++r) {
    int mb = (blockrow0 + r) * SS;
    int pq1 = mask_at(maskp, mode, mb + lane * 8);
    unsigned long long b1 = __ballot(pq1);
    int q = __popcll(b1);
    int base2 = 8 * (q - 1);
    int pq2 = mask_at(maskp, mode, mb + base2 + (lane & 7));
    unsigned long long b2 = __ballot((lane < 8) && pq2);
    lens[r] = base2 + __popcll(b2);
  }
  const int lenv = (g == 0) ? lens[0] : (g == 1) ? lens[1]
                 : (g == 2) ? lens[2] : lens[3];
  const int maxlen = max(max(lens[0], lens[1]), max(lens[2], lens[3]));
  const int nsteps = maxlen - 1;

  // --- E column pair in registers: E[i][col] = exp(trans[i][col]) ---
  float E1[TT], E2[TT];
#pragma unroll
  for (int k = 0; k < TT; ++k) {
    E1[k] = ex2(transp[k * TT + col1] * IL2);
    E2[k] = ex2(transp[k * TT + col2] * IL2);
  }

  // --- init alpha0 (linear domain) ---
  float p1 = ex2((startp[col1] + em[(size_t)rbS * TT + col1]) * IL2);
  float p2 = ex2((startp[col2] + em[(size_t)rbS * TT + col2]) * IL2);

  const int l0 = labels[rbS];
  float num = startp[l0] + em[rbS * TT + l0];   // natural-log units
  int C2 = 0;                                    // power-of-2 scale count
  int fl = l0;

  // --- prefetch rings ---
  // emv/tvv/emgv: data for steps t..t+7 (8 ahead). labv: labels 8..16 ahead.
  float emv1[8], emv2[8], tvv[8], emgv[8];
  int   labv[8];
#pragma unroll
  for (int u = 0; u < 8; ++u) {
    int sidx = rbS + 1 + u;
    emv1[u] = em[sidx * TT + col1];
    emv2[u] = em[sidx * TT + col2];
    int nl  = labels[sidx];
    tvv[u]  = transp[fl * TT + nl];
    emgv[u] = em[sidx * TT + nl];
    fl = nl;                                     // fl = label(8) after loop
  }
#pragma unroll
  for (int u = 0; u < 8; ++u) {
    int sl = 9 + u; if (sl > nsteps) sl = nsteps;
    labv[u] = labels[rbS + sl];                  // labels for steps 9..16
  }

  int t = 1;

#define STEP(u, FILL)                                                         \
  {                                                                           \
    const int s = t + (u);                                                    \
    float eex1 = ex2(emv1[u] * IL2);                                          \
    float eex2 = ex2(emv2[u] * IL2);                                          \
    float tadd = tvv[u] + emgv[u];                                            \
    bool live = (s < lenv);                                                   \
    num += live ? tadd : 0.0f;                                                \
    if (FILL) {                                                               \
      int sn = s + 8; if (sn > nsteps) sn = nsteps;                           \
      int sidx = rbS + sn;                                                    \
      emv1[u] = em[sidx * TT + col1];                                         \
      emv2[u] = em[sidx * TT + col2];                                         \
      int nl = labv[u];               /* label(s+8), loaded 8 steps ago */    \
      tvv[u]  = transp[fl * TT + nl];                                         \
      emgv[u] = em[sidx * TT + nl];                                           \
      int sl = s + 16; if (sl > nsteps) sl = nsteps;                          \
      labv[u] = labels[rbS + sl];                                             \
      fl = nl;                                                                \
    }                                                                         \
    smem[rowbase + wslot] = p1;                                               \
    smem[rowbase + wslot + 13] = p2;                                          \
    float pa[28];                                                             \
    {                                                                         \
      const float4* rp = (const float4*)&smem[rowbase];                       \
      *(float4*)&pa[0]  = rp[0]; *(float4*)&pa[4]  = rp[1];                   \
      *(float4*)&pa[8]  = rp[2]; *(float4*)&pa[12] = rp[3];                   \
      *(float4*)&pa[16] = rp[4]; *(float4*)&pa[20] = rp[5];                   \
      *(float4*)&pa[24] = rp[6];                                              \
    }                                                                         \
    float a0 = pa[0] * E1[0], a1 = pa[1] * E1[1];                             \
    float a2 = pa[2] * E1[2], a3 = pa[3] * E1[3];                             \
    float c0 = pa[0] * E2[0], c1 = pa[1] * E2[1];                             \
    float c2 = pa[2] * E2[2], c3 = pa[3] * E2[3];                             \
    _Pragma("unroll")                                                         \
    for (int k = 4; k < 24; k += 4) {                                         \
      a0 = fmaf(pa[k],     E1[k],     a0);                                    \
      a1 = fmaf(pa[k + 1], E1[k + 1], a1);                                    \
      a2 = fmaf(pa[k + 2], E1[k + 2], a2);                                    \
      a3 = fmaf(pa[k + 3], E1[k + 3], a3);                                    \
      c0 = fmaf(pa[k],     E2[k],     c0);                                    \
      c1 = fmaf(pa[k + 1], E2[k + 1], c1);                                    \
      c2 = fmaf(pa[k + 2], E2[k + 2], c2);                                    \
      c3 = fmaf(pa[k + 3], E2[k + 3], c3);                                    \
    }                                                                         \
    a0 = fmaf(pa[24], E1[24], a0);                                            \
    c0 = fmaf(pa[24], E2[24], c0);                                            \
    float s1 = (a0 + a1) + (a2 + a3);                                         \
    float s2 = (c0 + c1) + (c2 + c3);                                         \
    float p1n = s1 * eex1, p2n = s2 * eex2;                                   \
    p1 = live ? p1n : p1;                                                     \
    p2 = live ? p2n : p2;                                                     \
  }

  for (; t + 7 <= nsteps; t += 8) {
    STEP(0, 1) STEP(1, 1) STEP(2, 1) STEP(3, 1)
    STEP(4, 1) STEP(5, 1) STEP(6, 1) STEP(7, 1)
    // rescale: group max of p1 via swizzle butterfly (lanes 13-15 hold col-12 dup: safe)
    float pm = p1;
    pm = fmaxf(pm, __int_as_float(__builtin_amdgcn_ds_swizzle(__float_as_int(pm), 0x041F)));
    pm = fmaxf(pm, __int_as_float(__builtin_amdgcn_ds_swizzle(__float_as_int(pm), 0x081F)));
    pm = fmaxf(pm, __int_as_float(__builtin_amdgcn_ds_swizzle(__float_as_int(pm), 0x101F)));
    pm = fmaxf(pm, __int_as_float(__builtin_amdgcn_ds_swizzle(__float_as_int(pm), 0x201F)));
    int ef = (__float_as_int(pm) >> 23) & 0xFF;
    C2 += ef - 127;
    float sc = __int_as_float((254 - ef) << 23);   // exact 2^(127-ef)
    p1 *= sc; p2 *= sc;
  }
  {
    int rem = nsteps - t + 1;   // 0..7 remaining steps in ring slots 0..rem-1
    if (rem > 0) STEP(0, 0)
    if (rem > 1) STEP(1, 0)
    if (rem > 2) STEP(2, 0)
    if (rem > 3) STEP(3, 0)
    if (rem > 4) STEP(4, 0)
    if (rem > 5) STEP(5, 0)
    if (rem > 6) STEP(6, 0)
  }
#undef STEP

  // numerator tail
  const int lastlab = labels[rbS + lenv - 1];
  num += endp[lastlab];

  // denominator: term_j = p_j * exp(end_j); group-reduce over 13 active lanes
  float term = (lidx < 13 ? p1 * ex2(endp[col1] * IL2) : 0.0f)
             + (lidx < 12 ? p2 * ex2(endp[col2] * IL2) : 0.0f);
  term += __int_as_float(__builtin_amdgcn_ds_swizzle(__float_as_int(term), 0x041F));
  term += __int_as_float(__builtin_amdgcn_ds_swizzle(__float_as_int(term), 0x081F));
  term += __int_as_float(__builtin_amdgcn_ds_swizzle(__float_as_int(term), 0x101F));
  term += __int_as_float(__builtin_amdgcn_ds_swizzle(__float_as_int(term), 0x201F));
  float den = LN2F * (lg2(term) + (float)C2);

  if (lidx == 0) {
    wsr[rowid] = num - den;
    wsl[rowid] = (float)lenv;
  }
}

__global__ void crf_reduce(const float* __restrict__ wsr,
                           const float* __restrict__ wsl,
                           float* __restrict__ out)
{
  __shared__ float sr[256], sl[256];
  int t = threadIdx.x;
  float a = 0.0f, c = 0.0f;
  for (int i = t; i < BB; i += 256) { a += wsr[i]; c += wsl[i]; }
  sr[t] = a; sl[t] = c;
  __syncthreads();
  for (int k = 128; k > 0; k >>= 1) {
    if (t < k) { sr[t] += sr[t + k]; sl[t] += sl[t + k]; }
    __syncthreads();
  }
  if (t == 0) out[0] = sr[0] / sl[0];
}

extern "C" void kernel_launch(void* const* d_in, const int* in_sizes, int n_in,
                              void* d_out, int out_size, void* d_ws, size_t ws_size,
                              hipStream_t stream)
{
  const float* em = (const float*)d_in[0];
  const float* st = (const float*)d_in[1];
  const float* en = (const float*)d_in[2];
  const float* tr = (const float*)d_in[3];
  const int*   lb = (const int*)d_in[4];
  const void*  mk = d_in[5];
  float* wsr = (float*)d_ws;
  float* wsl = wsr + BB;
  crf_main<<<BB / 16, 256, 0, stream>>>(em, st, en, tr, lb, mk, wsr, wsl);
  crf_reduce<<<1, 256, 0, stream>>>(wsr, wsl, (float*)d_out);
}

// Round 4
// 116.885 us; speedup vs baseline: 2.4466x; 1.1539x over previous
//
#include <hip/hip_runtime.h>
#include <stdint.h>

#define TT 25
#define SS 512
#define BB 4096
#define RST 36
#define IL2 1.4426950408889634f
#define LN2F 0.6931471805599453f

__device__ __forceinline__ float ex2(float x){ return __builtin_amdgcn_exp2f(x); }
__device__ __forceinline__ float lg2(float x){ return __builtin_amdgcn_logf(x); }
__device__ __forceinline__ int iclampi(int x,int lo,int hi){ return min(max(x,lo),hi); }

template<int Q>
__device__ __forceinline__ float qb(float v){
  // broadcast quad-lane Q to all 4 lanes of each quad (VALU pipe, no LDS)
  return __int_as_float(__builtin_amdgcn_update_dpp(0, __float_as_int(v), Q*0x55, 0xF, 0xF, true));
}

#define SWZMAX(v,P) v = fmaxf(v, __int_as_float(__builtin_amdgcn_ds_swizzle(__float_as_int(v), P)))
#define SWZADD(v,P) v += __int_as_float(__builtin_amdgcn_ds_swizzle(__float_as_int(v), P))

// mask may arrive as bool(u8), int32, or float32 — detect from first element
__device__ __forceinline__ int mask_at(const void* m, int mode, int idx){
  if (mode == 1) return ((const int*)m)[idx] != 0;
  if (mode == 2) return ((const float*)m)[idx] != 0.0f;
  return ((const unsigned char*)m)[idx] != 0;
}

__global__ __launch_bounds__(256, 2)
void crf_main(const float* __restrict__ em, const float* __restrict__ startp,
              const float* __restrict__ endp, const float* __restrict__ transp,
              const int* __restrict__ labels, const void* __restrict__ maskp,
              float* __restrict__ wsr, float* __restrict__ wsl)
{
  __shared__ float smem[16 * RST];   // 4 waves x 4 groups x 36 floats
  const int tid  = threadIdx.x;
  const int w    = tid >> 6;
  const int lane = tid & 63;
  const int g    = lane >> 4;        // chain-group 0..3 within wave
  const int lidx = lane & 15;
  const int dir  = g & 1;            // 0 = forward, 1 = backward
  const int rsel = g >> 1;           // which of the wave's 2 rows
  const int row  = blockIdx.x * 8 + w * 2 + rsel;
  const int rbS  = row * SS;
  const int rowbase = (w * 4 + g) * RST;

  const int c1 = 2 * lidx, c2 = 2 * lidx + 1;      // adjacent col pair
  const bool v1 = (c1 < TT), v2 = (c2 < TT);
  const int c1c = v1 ? c1 : (TT - 1), c2c = v2 ? c2 : (TT - 1);
  const int ws2 = (lidx <= 12) ? 2 * lidx : (26 + 2 * (lidx - 13)); // idle dump 26..31

  // --- mask dtype detection ---
  const uint32_t w0 = ((const uint32_t*)maskp)[0];
  const int mode = (w0 == 1u) ? 1 : ((w0 == 0x3F800000u) ? 2 : 0);

  // --- lengths of the wave's two rows (2-round ballot probes) ---
  int lens[2];
  const int base2row = blockIdx.x * 8 + w * 2;
#pragma unroll
  for (int r = 0; r < 2; ++r) {
    int mb = (base2row + r) * SS;
    int pq1 = mask_at(maskp, mode, mb + lane * 8);
    unsigned long long b1 = __ballot(pq1);
    int q = __popcll(b1);
    int bs = 8 * (q - 1);
    int pq2 = mask_at(maskp, mode, mb + bs + (lane & 7));
    unsigned long long b2 = __ballot((lane < 8) && pq2);
    lens[r] = bs + __popcll(b2);
  }
  const int L = rsel ? lens[1] : lens[0];
  const int m = (L - 1) >> 1;
  const int iters = dir ? (L - 1 - m) : m;
  const int it0 = lens[0] - 1 - ((lens[0] - 1) >> 1);
  const int it1 = lens[1] - 1 - ((lens[1] - 1) >> 1);
  const int maxIters = max(it0, it1);   // bwd count >= fwd count

  // --- E slices: fwd E[i] = exp(trans[i][c]); bwd E[i] = exp(trans[c][i]) ---
  float E1[TT], E2[TT];
#pragma unroll
  for (int i = 0; i < TT; ++i) {
    float t1 = dir ? transp[c1c * TT + i] : transp[i * TT + c1c];
    float t2 = dir ? transp[c2c * TT + i] : transp[i * TT + c2c];
    E1[i] = v1 ? ex2(t1 * IL2) : 0.f;
    E2[i] = v2 ? ex2(t2 * IL2) : 0.f;
  }

  // --- init state: fwd alpha0 = exp(start+em0); bwd gamma_{L-1} = exp(end) ---
  float pf1 = startp[c1c] + em[(size_t)rbS * TT + c1c];
  float pf2 = startp[c2c] + em[(size_t)rbS * TT + c2c];
  float p1 = v1 ? ex2((dir ? endp[c1c] : pf1) * IL2) : 0.f;
  float p2 = v2 ? ex2((dir ? endp[c2c] : pf2) * IL2) : 0.f;

  // --- numerator init + label carry ---
  const int l0 = labels[rbS];
  const int lE = labels[rbS + L - 1];
  float num = dir ? endp[lE] : (startp[l0] + em[(size_t)rbS * TT + l0]);
  int C2 = 0;
  int carry = dir ? lE : l0;

  // --- prefetch rings (depth 8; labels 16 ahead for the dependent trans gather) ---
  float emv1[8], emv2[8], tadd[8];
  int labv[8];
#pragma unroll
  for (int u = 0; u < 8; ++u) {
    int t = dir ? (L - 1 - u) : (1 + u);
    t = iclampi(t, 1, L - 1);
    size_t eb = (size_t)(rbS + t) * TT;
    emv1[u] = em[eb + c1c];
    emv2[u] = em[eb + c2c];
    int ni = dir ? (L - 2 - u) : (1 + u);
    ni = iclampi(ni, 0, L - 1);
    int nl = labels[rbS + ni];
    int aL = dir ? nl : carry, bL = dir ? carry : nl;
    tadd[u] = transp[aL * TT + bL] + em[eb + bL];
    carry = nl;
  }
#pragma unroll
  for (int u = 0; u < 8; ++u) {
    int ni = dir ? (L - 2 - (u + 8)) : (1 + u + 8);
    ni = iclampi(ni, 0, L - 1);
    labv[u] = labels[rbS + ni];
  }

  int ubase = 0;

#define STEP(u, FILL)                                                         \
  {                                                                           \
    const int uu = ubase + (u);                                               \
    float e1 = ex2(emv1[u] * IL2), e2 = ex2(emv2[u] * IL2);                   \
    float ta = tadd[u];                                                       \
    bool live = uu < iters;                                                   \
    num += live ? ta : 0.f;                                                   \
    if (FILL) {                                                               \
      int vf = uu + 8;                                                        \
      int t = dir ? (L - 1 - vf) : (1 + vf);                                  \
      t = iclampi(t, 1, L - 1);                                               \
      size_t eb = (size_t)(rbS + t) * TT;                                     \
      emv1[u] = em[eb + c1c];                                                 \
      emv2[u] = em[eb + c2c];                                                 \
      int nl = labv[u];                                                       \
      int aL = dir ? nl : carry, bL = dir ? carry : nl;                       \
      tadd[u] = transp[aL * TT + bL] + em[eb + bL];                           \
      int ni = dir ? (L - 2 - (vf + 8)) : (1 + vf + 8);                       \
      ni = iclampi(ni, 0, L - 1);                                             \
      labv[u] = labels[rbS + ni];                                             \
      carry = nl;                                                             \
    }                                                                         \
    float w1 = dir ? p1 * e1 : p1, w2v = dir ? p2 * e2 : p2;                  \
    ((float2*)smem)[(rowbase + ws2) >> 1] = make_float2(w1, w2v);             \
    const float4* rp = (const float4*)&smem[rowbase + ((lane & 3) << 3)];     \
    float4 x0 = rp[0], x1 = rp[1];                                            \
    float d1a = 0.f, d1b = 0.f, d2a = 0.f, d2b = 0.f, pv;                     \
    pv = qb<0>(x0.x); d1a = fmaf(pv, E1[0],  d1a); d2a = fmaf(pv, E2[0],  d2a); \
    pv = qb<0>(x0.y); d1b = fmaf(pv, E1[1],  d1b); d2b = fmaf(pv, E2[1],  d2b); \
    pv = qb<0>(x0.z); d1a = fmaf(pv, E1[2],  d1a); d2a = fmaf(pv, E2[2],  d2a); \
    pv = qb<0>(x0.w); d1b = fmaf(pv, E1[3],  d1b); d2b = fmaf(pv, E2[3],  d2b); \
    pv = qb<0>(x1.x); d1a = fmaf(pv, E1[4],  d1a); d2a = fmaf(pv, E2[4],  d2a); \
    pv = qb<0>(x1.y); d1b = fmaf(pv, E1[5],  d1b); d2b = fmaf(pv, E2[5],  d2b); \
    pv = qb<0>(x1.z); d1a = fmaf(pv, E1[6],  d1a); d2a = fmaf(pv, E2[6],  d2a); \
    pv = qb<0>(x1.w); d1b = fmaf(pv, E1[7],  d1b); d2b = fmaf(pv, E2[7],  d2b); \
    pv = qb<1>(x0.x); d1a = fmaf(pv, E1[8],  d1a); d2a = fmaf(pv, E2[8],  d2a); \
    pv = qb<1>(x0.y); d1b = fmaf(pv, E1[9],  d1b); d2b = fmaf(pv, E2[9],  d2b); \
    pv = qb<1>(x0.z); d1a = fmaf(pv, E1[10], d1a); d2a = fmaf(pv, E2[10], d2a); \
    pv = qb<1>(x0.w); d1b = fmaf(pv, E1[11], d1b); d2b = fmaf(pv, E2[11], d2b); \
    pv = qb<1>(x1.x); d1a = fmaf(pv, E1[12], d1a); d2a = fmaf(pv, E2[12], d2a); \
    pv = qb<1>(x1.y); d1b = fmaf(pv, E1[13], d1b); d2b = fmaf(pv, E2[13], d2b); \
    pv = qb<1>(x1.z); d1a = fmaf(pv, E1[14], d1a); d2a = fmaf(pv, E2[14], d2a); \
    pv = qb<1>(x1.w); d1b = fmaf(pv, E1[15], d1b); d2b = fmaf(pv, E2[15], d2b); \
    pv = qb<2>(x0.x); d1a = fmaf(pv, E1[16], d1a); d2a = fmaf(pv, E2[16], d2a); \
    pv = qb<2>(x0.y); d1b = fmaf(pv, E1[17], d1b); d2b = fmaf(pv, E2[17], d2b); \
    pv = qb<2>(x0.z); d1a = fmaf(pv, E1[18], d1a); d2a = fmaf(pv, E2[18], d2a); \
    pv = qb<2>(x0.w); d1b = fmaf(pv, E1[19], d1b); d2b = fmaf(pv, E2[19], d2b); \
    pv = qb<2>(x1.x); d1a = fmaf(pv, E1[20], d1a); d2a = fmaf(pv, E2[20], d2a); \
    pv = qb<2>(x1.y); d1b = fmaf(pv, E1[21], d1b); d2b = fmaf(pv, E2[21], d2b); \
    pv = qb<2>(x1.z); d1a = fmaf(pv, E1[22], d1a); d2a = fmaf(pv, E2[22], d2a); \
    pv = qb<2>(x1.w); d1b = fmaf(pv, E1[23], d1b); d2b = fmaf(pv, E2[23], d2b); \
    pv = qb<3>(x0.x); d1a = fmaf(pv, E1[24], d1a); d2a = fmaf(pv, E2[24], d2a); \
    float d1 = d1a + d1b, d2 = d2a + d2b;                                     \
    float p1n = dir ? d1 : d1 * e1, p2n = dir ? d2 : d2 * e2;                 \
    p1 = live ? p1n : p1; p2 = live ? p2n : p2;                               \
  }

#define RESCALE {                                                             \
    float mx = fmaxf(p1, p2);                                                 \
    SWZMAX(mx, 0x041F); SWZMAX(mx, 0x081F);                                   \
    SWZMAX(mx, 0x101F); SWZMAX(mx, 0x201F);                                   \
    int ef = (__float_as_int(mx) >> 23) & 0xFF;                               \
    C2 += ef - 127;                                                           \
    float sc = __int_as_float((254 - ef) << 23);                              \
    p1 *= sc; p2 *= sc; }

  for (; ubase + 8 <= maxIters; ubase += 8) {
    STEP(0, 1) STEP(1, 1) STEP(2, 1) STEP(3, 1)
    STEP(4, 1) STEP(5, 1) STEP(6, 1) STEP(7, 1)
    RESCALE
  }
  {
    int rem = maxIters - ubase;
    if (rem > 0) STEP(0, 0)
    if (rem > 1) STEP(1, 0)
    if (rem > 2) STEP(2, 0)
    if (rem > 3) STEP(3, 0)
    if (rem > 4) STEP(4, 0)
    if (rem > 5) STEP(5, 0)
    if (rem > 6) STEP(6, 0)
  }
  RESCALE   // normalize before the alpha·gamma dot (avoid fp32 overflow)

#undef STEP
#undef RESCALE

  // --- epilogue: combine fwd (g even) with bwd partner (g^1) in-wave via LDS ---
  ((float2*)smem)[(rowbase + ws2) >> 1] = make_float2(p1, p2);
  smem[rowbase + 32] = num;
  smem[rowbase + 33] = __int_as_float(C2);
  // same-wave LDS ordering via lgkmcnt (no barrier needed)
  const int pbase = (w * 4 + (g ^ 1)) * RST;
  float2 qq = ((float2*)smem)[(pbase + ws2) >> 1];
  float prod = p1 * qq.x + p2 * qq.y;
  SWZADD(prod, 0x041F); SWZADD(prod, 0x081F);
  SWZADD(prod, 0x101F); SWZADD(prod, 0x201F);
  float onum = smem[pbase + 32];
  int oC2 = __float_as_int(smem[pbase + 33]);
  if (lidx == 0 && dir == 0) {
    float den = LN2F * (lg2(prod) + (float)(C2 + oC2));
    wsr[row] = (num + onum) - den;
    wsl[row] = (float)L;
  }
}

__global__ void crf_reduce(const float* __restrict__ wsr,
                           const float* __restrict__ wsl,
                           float* __restrict__ out)
{
  __shared__ float sr[256], sl[256];
  int t = threadIdx.x;
  float a = 0.0f, c = 0.0f;
  for (int i = t; i < BB; i += 256) { a += wsr[i]; c += wsl[i]; }
  sr[t] = a; sl[t] = c;
  __syncthreads();
  for (int k = 128; k > 0; k >>= 1) {
    if (t < k) { sr[t] += sr[t + k]; sl[t] += sl[t + k]; }
    __syncthreads();
  }
  if (t == 0) out[0] = sr[0] / sl[0];
}

extern "C" void kernel_launch(void* const* d_in, const int* in_sizes, int n_in,
                              void* d_out, int out_size, void* d_ws, size_t ws_size,
                              hipStream_t stream)
{
  const float* em = (const float*)d_in[0];
  const float* st = (const float*)d_in[1];
  const float* en = (const float*)d_in[2];
  const float* tr = (const float*)d_in[3];
  const int*   lb = (const int*)d_in[4];
  const void*  mk = d_in[5];
  float* wsr = (float*)d_ws;
  float* wsl = wsr + BB;
  crf_main<<<BB / 8, 256, 0, stream>>>(em, st, en, tr, lb, mk, wsr, wsl);
  crf_reduce<<<1, 256, 0, stream>>>(wsr, wsl, (float*)d_out);
}